// Round 6
// baseline (308.165 us; speedup 1.0000x reference)
//
#include <hip/hip_runtime.h>
#include <hip/hip_bf16.h>
#include <stdint.h>

typedef unsigned short u16;
typedef unsigned int u32;
typedef __attribute__((ext_vector_type(8))) short short8;
typedef __attribute__((ext_vector_type(4))) float f32x4;

#define T_TOK 2048
#define H_DIM 1024
#define F_DIM 4096
#define E_NUM 8
#define M_SLOT 4096
#define MAXTILES 40
#define KSPLIT 2

__device__ __forceinline__ u16 f2bf(float f){
  union { float f; u32 u; } v; v.f = f;
  return (u16)((v.u + 0x7FFFu + ((v.u >> 16) & 1u)) >> 16);
}

// ---------------- router: logits = x @ rw, top2, softmax ----------------
__global__ __launch_bounds__(256) void router_kernel(
    const float* __restrict__ x, const float* __restrict__ rw,
    int* __restrict__ tok_e, float* __restrict__ tok_p){
  __shared__ float wlds[E_NUM * H_DIM];
  int tid = threadIdx.x;
  for (int i = tid; i < H_DIM * E_NUM; i += 256){
    int h = i >> 3, e = i & 7;
    wlds[e * H_DIM + h] = rw[i];
  }
  __syncthreads();
  int wave = tid >> 6, lane = tid & 63;
  int t = blockIdx.x * 4 + wave;
  const float* xr = x + (size_t)t * H_DIM;
  float acc[E_NUM];
  #pragma unroll
  for (int e = 0; e < E_NUM; e++) acc[e] = 0.f;
  for (int i = 0; i < H_DIM / 64; i++){
    float xv = xr[lane + 64 * i];
    #pragma unroll
    for (int e = 0; e < E_NUM; e++) acc[e] += xv * wlds[e * H_DIM + lane + 64 * i];
  }
  #pragma unroll
  for (int e = 0; e < E_NUM; e++){
    float r = acc[e];
    #pragma unroll
    for (int off = 32; off; off >>= 1) r += __shfl_xor(r, off, 64);
    acc[e] = r;
  }
  if (lane == 0){
    float l0 = acc[0]; int e0 = 0;
    #pragma unroll
    for (int e = 1; e < E_NUM; e++) if (acc[e] > l0){ l0 = acc[e]; e0 = e; }
    float l1 = -INFINITY; int e1 = 0;
    #pragma unroll
    for (int e = 0; e < E_NUM; e++) if (e != e0 && acc[e] > l1){ l1 = acc[e]; e1 = e; }
    float ex = expf(l1 - l0);
    float inv = 1.f / (1.f + ex);
    tok_e[2*t] = e0; tok_e[2*t+1] = e1;
    tok_p[2*t] = inv; tok_p[2*t+1] = ex * inv;
  }
}

// ---------------- histogram ----------------
__global__ void hist_kernel(const int* __restrict__ tok_e, u32* __restrict__ partial){
  int lane = threadIdx.x & 63;
  int m = blockIdx.x * 64 + lane;
  int e = tok_e[m];
  #pragma unroll
  for (int ee = 0; ee < E_NUM; ee++){
    unsigned long long mk = __ballot(e == ee);
    if (lane == ee) partial[blockIdx.x * E_NUM + ee] = (u32)__popcll(mk);
  }
}

// ---------------- scan + tile table (128-row tiles) ----------------
__global__ void scan_kernel(const u32* __restrict__ partial, u32* __restrict__ baseb,
                            int4* __restrict__ tiles, int* __restrict__ ntiles){
  int lane = threadIdx.x;  // 64 threads
  u32 exc[E_NUM], tot[E_NUM];
  #pragma unroll
  for (int e = 0; e < E_NUM; e++){
    u32 v = partial[lane * E_NUM + e];
    u32 own = v;
    #pragma unroll
    for (int off = 1; off < 64; off <<= 1){
      u32 tu = __shfl_up(v, off, 64);
      if (lane >= off) v += tu;
    }
    exc[e] = v - own;
    tot[e] = __shfl(v, 63, 64);
  }
  u32 offs[E_NUM + 1]; offs[0] = 0;
  #pragma unroll
  for (int e = 0; e < E_NUM; e++) offs[e+1] = offs[e] + tot[e];
  #pragma unroll
  for (int e = 0; e < E_NUM; e++) baseb[lane * E_NUM + e] = offs[e] + exc[e];
  if (lane == 0){
    int nt = 0;
    for (int e = 0; e < E_NUM; e++){
      int cnt = (int)tot[e];
      for (int r0 = 0; r0 < cnt; r0 += 128){
        tiles[nt] = make_int4((int)offs[e] + r0, min(128, cnt - r0), e, 0);
        nt++;
      }
    }
    *ntiles = nt;
  }
}

// ---------------- scatter ----------------
__global__ void scatter_kernel(const int* __restrict__ tok_e, const u32* __restrict__ baseb,
                               int* __restrict__ dest){
  int lane = threadIdx.x & 63;
  int m = blockIdx.x * 64 + lane;
  int e = tok_e[m];
  unsigned long long eq = 0;
  #pragma unroll
  for (int ee = 0; ee < E_NUM; ee++){
    unsigned long long mk = __ballot(e == ee);
    if (e == ee) eq = mk;
  }
  u32 rank = (u32)__popcll(eq & ((1ull << lane) - 1ull));
  dest[m] = (int)(baseb[blockIdx.x * E_NUM + e] + rank);
}

// ---------------- gather x rows -> grouped bf16 ----------------
__global__ __launch_bounds__(256) void gather_kernel(const float* __restrict__ x,
                                                     const int* __restrict__ dest,
                                                     u16* __restrict__ xg){
  int m = blockIdx.x;
  int d = dest[m];
  const float4* xr = (const float4*)(x + (size_t)(m >> 1) * H_DIM);
  float4 v = xr[threadIdx.x];
  ushort4 o;
  o.x = f2bf(v.x); o.y = f2bf(v.y); o.z = f2bf(v.z); o.w = f2bf(v.w);
  ((ushort4*)(xg + (size_t)d * H_DIM))[threadIdx.x] = o;
}

// ---------------- grouped GEMM, m97 structure + fused f32-weight staging ----
// 128x128 tile, BK=64, 256 threads (4 waves 2x2), 32 KB LDS (single buffer),
// 3 blocks/CU. A [*][KSTRIDE] bf16 row-major. W [E][KSTRIDE][N] f32 (K-major,
// the ORIGINAL layout -- no pre-transpose).
// Staging is register-based (T14 pattern): loads issued at iter top (latency
// hidden under MFMA), converted+ds_written after barrier1, published at barrier2.
// LDS layout (both A and B tiles): [128 rows][64 u16], row-major with XOR
// swizzle byte ^= (row&7)<<4 -- identical read path to round 5 (proven).
template<int N, int KSTRIDE, int NT, bool GELU_EP>
__global__ __launch_bounds__(256, 3) void gemmf(
    const u16* __restrict__ A, const float* __restrict__ W,
    const int4* __restrict__ tiles, const int* __restrict__ ntiles_p,
    float* __restrict__ outF, u16* __restrict__ outB, size_t zstride){
  if ((int)blockIdx.y >= *ntiles_p) return;
  int4 ti = tiles[blockIdx.y];
  int row0 = ti.x, nrows = ti.y, e = ti.z;
  int col0 = blockIdx.x * 128;
  size_t kofs = (size_t)blockIdx.z * ((size_t)NT * 64);
  const float* We = W + (size_t)e * KSTRIDE * N;
  float* outFz = outF + (size_t)blockIdx.z * zstride;

  __shared__ __align__(16) u16 As[128 * 64];
  __shared__ __align__(16) u16 Bs[128 * 64];
  int lane = threadIdx.x & 63, wid = threadIdx.x >> 6;
  int wr = wid >> 1, wc = wid & 1;

  f32x4 acc[4][4];
  #pragma unroll
  for (int m = 0; m < 4; m++)
    #pragma unroll
    for (int n = 0; n < 4; n++) acc[m][n] = (f32x4)0.f;

  // A: same source-swizzle/linear-dest mapping as the proven gload path
  int skx = ((lane & 7) * 16) ^ ((lane >> 3) << 4);
  // B: thread owns (n, kh): n fixed, k = kh*32 + 0..31
  int kh = lane & 1;
  int nn = wid * 32 + (lane >> 1);
  int bswz = (nn & 7) << 4;

  short8 areg[4];
  float breg[32];

  auto issue = [&](int kt){
    size_t kb = kofs + (size_t)kt * 64;
    #pragma unroll
    for (int i = 0; i < 4; i++){
      int row = i * 32 + (wid << 3) + (lane >> 3);
      areg[i] = *(const short8*)((const char*)(A + (size_t)(row0 + row) * KSTRIDE + kb) + skx);
    }
    const float* gp = We + (kb + (size_t)(kh * 32)) * N + col0 + nn;
    #pragma unroll
    for (int j = 0; j < 32; j++) breg[j] = gp[(size_t)j * N];
  };

  auto commit = [&](){
    #pragma unroll
    for (int i = 0; i < 4; i++)
      *(short8*)((char*)As + i * 4096 + wid * 1024 + lane * 16) = areg[i];
    #pragma unroll
    for (int i2 = 0; i2 < 4; i2++){
      short8 v;
      #pragma unroll
      for (int j = 0; j < 8; j++) v[j] = (short)f2bf(breg[i2 * 8 + j]);
      *(short8*)((char*)Bs + nn * 128 + ((kh * 64 + i2 * 16) ^ bswz)) = v;
    }
  };

  issue(0); commit();
  __syncthreads();

  for (int kt = 0; kt < NT; kt++){
    if (kt + 1 < NT) issue(kt + 1);          // loads in flight under compute
    #pragma unroll
    for (int kk = 0; kk < 2; kk++){
      short8 a[4], b[4];
      #pragma unroll
      for (int m = 0; m < 4; m++){
        int row = wr * 64 + m * 16 + (lane & 15);
        int byte_ = row * 128 + ((kk * 64 + (lane >> 4) * 16) ^ ((row & 7) << 4));
        a[m] = *(const short8*)((const char*)As + byte_);
      }
      #pragma unroll
      for (int n = 0; n < 4; n++){
        int row = wc * 64 + n * 16 + (lane & 15);
        int byte_ = row * 128 + ((kk * 64 + (lane >> 4) * 16) ^ ((row & 7) << 4));
        b[n] = *(const short8*)((const char*)Bs + byte_);
      }
      #pragma unroll
      for (int m = 0; m < 4; m++)
        #pragma unroll
        for (int n = 0; n < 4; n++)
          acc[m][n] = __builtin_amdgcn_mfma_f32_16x16x32_bf16(a[m], b[n], acc[m][n], 0, 0, 0);
    }
    __syncthreads();                          // readers done with LDS(kt)
    if (kt + 1 < NT) commit();                // cvt + ds_write tile kt+1
    __syncthreads();                          // staged tile visible
  }

  #pragma unroll
  for (int m = 0; m < 4; m++){
    int rloc = wr * 64 + m * 16 + (lane >> 4) * 4;
    #pragma unroll
    for (int j = 0; j < 4; j++){
      int rr = rloc + j;
      if (rr < nrows){
        size_t rowg = (size_t)(row0 + rr);
        #pragma unroll
        for (int n = 0; n < 4; n++){
          int cc = col0 + wc * 64 + n * 16 + (lane & 15);
          float v = acc[m][n][j];
          if (GELU_EP){
            float g = v * 0.5f * (1.f + erff(v * 0.70710678118f));
            outFz[rowg * N + cc] = g;
            outB[rowg * N + cc] = f2bf(g);
          } else {
            outFz[rowg * N + cc] = v;
          }
        }
      }
    }
  }
}

// ---------------- combine: sum KSPLIT partials, weighted ----------------
__global__ __launch_bounds__(256) void combine_kernel(const float* __restrict__ yp,
                                                      const int* __restrict__ dest,
                                                      const float* __restrict__ tok_p,
                                                      float* __restrict__ out){
  int t = blockIdx.x;
  int d0 = dest[2*t], d1 = dest[2*t+1];
  float p0 = tok_p[2*t], p1 = tok_p[2*t+1];
  float4 r; r.x = 0.f; r.y = 0.f; r.z = 0.f; r.w = 0.f;
  #pragma unroll
  for (int s = 0; s < KSPLIT; s++){
    float4 a = ((const float4*)(yp + ((size_t)s * M_SLOT + d0) * H_DIM))[threadIdx.x];
    float4 b = ((const float4*)(yp + ((size_t)s * M_SLOT + d1) * H_DIM))[threadIdx.x];
    r.x += p0*a.x + p1*b.x; r.y += p0*a.y + p1*b.y;
    r.z += p0*a.z + p1*b.z; r.w += p0*a.w + p1*b.w;
  }
  ((float4*)(out + (size_t)t * H_DIM))[threadIdx.x] = r;
}

extern "C" void kernel_launch(void* const* d_in, const int* in_sizes, int n_in,
                              void* d_out, int out_size, void* d_ws, size_t ws_size,
                              hipStream_t stream) {
  const float* x  = (const float*)d_in[0];
  const float* rw = (const float*)d_in[1];
  const float* w1 = (const float*)d_in[2];
  const float* w2 = (const float*)d_in[3];
  float* out_mlp  = (float*)d_out;
  float* out_gelu = (float*)d_out + (size_t)T_TOK * H_DIM;

  char* ws = (char*)d_ws;
  u16*   xg    = (u16*)(ws + 0);                     // [M+128][H] bf16, 8.65 MB
  u16*   gb    = (u16*)(ws + (9u << 20));            // [M+128][F] bf16, 34.6 MB
  float* ypart = (float*)(ws + (48u << 20));         // [2][M][H] f32,  33.6 MB
  char*  small = ws + (84u << 20);
  int*   tok_e = (int*)(small);
  float* tok_p = (float*)(small + 16384);
  int*   dest  = (int*)(small + 32768);
  u32*   partial = (u32*)(small + 49152);
  u32*   baseb   = (u32*)(small + 51200);
  int4*  tiles   = (int4*)(small + 53248);
  int*   ntiles  = (int*)(small + 54272);

  router_kernel<<<T_TOK/4, 256, 0, stream>>>(x, rw, tok_e, tok_p);
  hist_kernel<<<M_SLOT/64, 64, 0, stream>>>(tok_e, partial);
  scan_kernel<<<1, 64, 0, stream>>>(partial, baseb, tiles, ntiles);
  scatter_kernel<<<M_SLOT/64, 64, 0, stream>>>(tok_e, baseb, dest);
  gather_kernel<<<M_SLOT, 256, 0, stream>>>(x, dest, xg);
  // GEMM1: [M,1024] @ w1[e] ([1024][4096] f32, direct) + GELU
  gemmf<F_DIM, H_DIM, 16, true><<<dim3(F_DIM/128, MAXTILES, 1), 256, 0, stream>>>(
      xg, w1, tiles, ntiles, out_gelu, gb, 0);
  // GEMM2: [M,4096] @ w2[e] ([4096][1024] f32, direct), split-K=2
  gemmf<H_DIM, F_DIM, 32, false><<<dim3(H_DIM/128, MAXTILES, KSPLIT), 256, 0, stream>>>(
      gb, w2, tiles, ntiles, ypart, nullptr, (size_t)M_SLOT * H_DIM);
  combine_kernel<<<T_TOK, 256, 0, stream>>>(ypart, dest, tok_p, out_mlp);
}

// Round 7
// 285.033 us; speedup vs baseline: 1.0812x; 1.0812x over previous
//
#include <hip/hip_runtime.h>
#include <hip/hip_bf16.h>
#include <stdint.h>

typedef unsigned short u16;
typedef unsigned int u32;
typedef __attribute__((ext_vector_type(8))) short short8;
typedef __attribute__((ext_vector_type(4))) float f32x4;

#define T_TOK 2048
#define H_DIM 1024
#define F_DIM 4096
#define E_NUM 8
#define M_SLOT 4096
#define MAXTILES 40
#define KSPLIT 2

__device__ __forceinline__ u16 f2bf(float f){
  union { float f; u32 u; } v; v.f = f;
  return (u16)((v.u + 0x7FFFu + ((v.u >> 16) & 1u)) >> 16);
}

__device__ __forceinline__ void gload_lds16(const void* g, void* l){
  __builtin_amdgcn_global_load_lds(
      (const __attribute__((address_space(1))) u32*)g,
      (__attribute__((address_space(3))) u32*)l, 16, 0, 0);
}

// ---------------- router: logits = x @ rw, top2, softmax ----------------
__global__ __launch_bounds__(256) void router_kernel(
    const float* __restrict__ x, const float* __restrict__ rw,
    int* __restrict__ tok_e, float* __restrict__ tok_p){
  __shared__ float wlds[E_NUM * H_DIM];
  int tid = threadIdx.x;
  for (int i = tid; i < H_DIM * E_NUM; i += 256){
    int h = i >> 3, e = i & 7;
    wlds[e * H_DIM + h] = rw[i];
  }
  __syncthreads();
  int wave = tid >> 6, lane = tid & 63;
  int t = blockIdx.x * 4 + wave;
  const float* xr = x + (size_t)t * H_DIM;
  float acc[E_NUM];
  #pragma unroll
  for (int e = 0; e < E_NUM; e++) acc[e] = 0.f;
  for (int i = 0; i < H_DIM / 64; i++){
    float xv = xr[lane + 64 * i];
    #pragma unroll
    for (int e = 0; e < E_NUM; e++) acc[e] += xv * wlds[e * H_DIM + lane + 64 * i];
  }
  #pragma unroll
  for (int e = 0; e < E_NUM; e++){
    float r = acc[e];
    #pragma unroll
    for (int off = 32; off; off >>= 1) r += __shfl_xor(r, off, 64);
    acc[e] = r;
  }
  if (lane == 0){
    float l0 = acc[0]; int e0 = 0;
    #pragma unroll
    for (int e = 1; e < E_NUM; e++) if (acc[e] > l0){ l0 = acc[e]; e0 = e; }
    float l1 = -INFINITY; int e1 = 0;
    #pragma unroll
    for (int e = 0; e < E_NUM; e++) if (e != e0 && acc[e] > l1){ l1 = acc[e]; e1 = e; }
    float ex = expf(l1 - l0);
    float inv = 1.f / (1.f + ex);
    tok_e[2*t] = e0; tok_e[2*t+1] = e1;
    tok_p[2*t] = inv; tok_p[2*t+1] = ex * inv;
  }
}

// ---------------- histogram ----------------
__global__ void hist_kernel(const int* __restrict__ tok_e, u32* __restrict__ partial){
  int lane = threadIdx.x & 63;
  int m = blockIdx.x * 64 + lane;
  int e = tok_e[m];
  #pragma unroll
  for (int ee = 0; ee < E_NUM; ee++){
    unsigned long long mk = __ballot(e == ee);
    if (lane == ee) partial[blockIdx.x * E_NUM + ee] = (u32)__popcll(mk);
  }
}

// ---------------- scan + tile table (128-row tiles) ----------------
__global__ void scan_kernel(const u32* __restrict__ partial, u32* __restrict__ baseb,
                            int4* __restrict__ tiles, int* __restrict__ ntiles){
  int lane = threadIdx.x;  // 64 threads
  u32 exc[E_NUM], tot[E_NUM];
  #pragma unroll
  for (int e = 0; e < E_NUM; e++){
    u32 v = partial[lane * E_NUM + e];
    u32 own = v;
    #pragma unroll
    for (int off = 1; off < 64; off <<= 1){
      u32 tu = __shfl_up(v, off, 64);
      if (lane >= off) v += tu;
    }
    exc[e] = v - own;
    tot[e] = __shfl(v, 63, 64);
  }
  u32 offs[E_NUM + 1]; offs[0] = 0;
  #pragma unroll
  for (int e = 0; e < E_NUM; e++) offs[e+1] = offs[e] + tot[e];
  #pragma unroll
  for (int e = 0; e < E_NUM; e++) baseb[lane * E_NUM + e] = offs[e] + exc[e];
  if (lane == 0){
    int nt = 0;
    for (int e = 0; e < E_NUM; e++){
      int cnt = (int)tot[e];
      for (int r0 = 0; r0 < cnt; r0 += 128){
        tiles[nt] = make_int4((int)offs[e] + r0, min(128, cnt - r0), e, 0);
        nt++;
      }
    }
    *ntiles = nt;
  }
}

// ---------------- scatter ----------------
__global__ void scatter_kernel(const int* __restrict__ tok_e, const u32* __restrict__ baseb,
                               int* __restrict__ dest){
  int lane = threadIdx.x & 63;
  int m = blockIdx.x * 64 + lane;
  int e = tok_e[m];
  unsigned long long eq = 0;
  #pragma unroll
  for (int ee = 0; ee < E_NUM; ee++){
    unsigned long long mk = __ballot(e == ee);
    if (e == ee) eq = mk;
  }
  u32 rank = (u32)__popcll(eq & ((1ull << lane) - 1ull));
  dest[m] = (int)(baseb[blockIdx.x * E_NUM + e] + rank);
}

// ---------------- gather x rows -> grouped bf16 ----------------
__global__ __launch_bounds__(256) void gather_kernel(const float* __restrict__ x,
                                                     const int* __restrict__ dest,
                                                     u16* __restrict__ xg){
  int m = blockIdx.x;
  int d = dest[m];
  const float4* xr = (const float4*)(x + (size_t)(m >> 1) * H_DIM);
  float4 v = xr[threadIdx.x];
  ushort4 o;
  o.x = f2bf(v.x); o.y = f2bf(v.y); o.z = f2bf(v.z); o.w = f2bf(v.w);
  ((ushort4*)(xg + (size_t)d * H_DIM))[threadIdx.x] = o;
}

// ---------------- grouped GEMM, direct f32 weights, LDS cvt pass ----------
// 128x128 tile, BK=64, 256 threads (4 waves 2x2), 80 KB LDS, 2 blocks/CU.
// A [*][KSTRIDE] bf16 row-major (proven gload path, double-buffered).
// W [E][KSTRIDE][N] f32 in ORIGINAL layout (no pre-transpose):
//   stage raw f32 [64k][128n] tile via global_load_lds (linear, coalesced),
//   then in-LDS cvt/transpose pass writes swizzled [n][k] bf16 tile Bs
//   identical to round-5's proven MFMA read layout.
// Per tile: {issue gloads(kt+1)} compute(kt) | sync(vmcnt0+publish) | cvt | sync.
template<int N, int KSTRIDE, int NT, bool GELU_EP>
__global__ __launch_bounds__(256, 2) void gemmw(
    const u16* __restrict__ A, const float* __restrict__ W,
    const int4* __restrict__ tiles, const int* __restrict__ ntiles_p,
    float* __restrict__ outF, u16* __restrict__ outB, size_t zstride){
  if ((int)blockIdx.y >= *ntiles_p) return;
  int4 ti = tiles[blockIdx.y];
  int row0 = ti.x, nrows = ti.y, e = ti.z;
  int col0 = blockIdx.x * 128;
  size_t kofs = (size_t)blockIdx.z * ((size_t)NT * 64);
  const float* We = W + (size_t)e * (size_t)KSTRIDE * N;
  float* outFz = outF + (size_t)blockIdx.z * zstride;

  __shared__ __align__(16) u16 As[2][128 * 64];   // 32 KB (dbuf)
  __shared__ __align__(16) u16 Bs[128 * 64];      // 16 KB (swizzled bf16 [n][k])
  __shared__ __align__(16) float Bf[64 * 128];    // 32 KB (raw f32 [k][n])

  int tid = threadIdx.x, lane = tid & 63, wid = tid >> 6;
  int wr = wid >> 1, wc = wid & 1;

  // A source swizzle (r5 proven): linear LDS dest + inverse-swizzled source
  int skx = ((lane & 7) * 16) ^ ((lane >> 3) << 4);
  // cvt-pass ownership: k-rows rb*8..rb*8+7, n-cols cb*4..cb*4+3
  int rb = tid & 7, cb = tid >> 3;

  f32x4 acc[4][4];
  #pragma unroll
  for (int m = 0; m < 4; m++)
    #pragma unroll
    for (int n = 0; n < 4; n++) acc[m][n] = (f32x4)0.f;

  auto issueA = [&](int kt, int p){
    size_t kb = kofs + (size_t)kt * 64;
    #pragma unroll
    for (int i = 0; i < 4; i++){
      int row = i * 32 + (wid << 3) + (lane >> 3);
      gload_lds16((const char*)(A + (size_t)(row0 + row) * KSTRIDE + kb) + skx,
                  (char*)&As[p][0] + i * 4096 + wid * 1024);
    }
  };
  auto issueB = [&](int kt){
    size_t kb = kofs + (size_t)kt * 64;
    #pragma unroll
    for (int i = 0; i < 8; i++){
      int g = i * 4 + wid;                     // 2 k-rows per gload
      const float* src = We + (kb + (size_t)(g * 2 + (lane >> 5))) * N
                            + col0 + (lane & 31) * 4;
      gload_lds16(src, (char*)Bf + g * 1024);
    }
  };
  auto cvtB = [&](){
    float f[8][4];
    #pragma unroll
    for (int j = 0; j < 8; j++)
      *(float4*)&f[j][0] = *(const float4*)((const char*)Bf + (rb * 8 + j) * 512 + cb * 16);
    #pragma unroll
    for (int i = 0; i < 4; i++){
      int n = cb * 4 + i;
      short8 v;
      #pragma unroll
      for (int j = 0; j < 8; j++) v[j] = (short)f2bf(f[j][i]);
      *(short8*)((char*)Bs + n * 128 + ((rb * 16) ^ ((n & 7) << 4))) = v;
    }
  };
  auto compute = [&](int p){
    #pragma unroll
    for (int kk = 0; kk < 2; kk++){
      short8 a[4], b[4];
      #pragma unroll
      for (int m = 0; m < 4; m++){
        int row = wr * 64 + m * 16 + (lane & 15);
        int byte_ = row * 128 + ((kk * 64 + (lane >> 4) * 16) ^ ((row & 7) << 4));
        a[m] = *(const short8*)((const char*)&As[p][0] + byte_);
      }
      #pragma unroll
      for (int n = 0; n < 4; n++){
        int row = wc * 64 + n * 16 + (lane & 15);
        int byte_ = row * 128 + ((kk * 64 + (lane >> 4) * 16) ^ ((row & 7) << 4));
        b[n] = *(const short8*)((const char*)Bs + byte_);
      }
      #pragma unroll
      for (int m = 0; m < 4; m++)
        #pragma unroll
        for (int n = 0; n < 4; n++)
          acc[m][n] = __builtin_amdgcn_mfma_f32_16x16x32_bf16(a[m], b[n], acc[m][n], 0, 0, 0);
    }
  };

  issueA(0, 0); issueB(0);
  __syncthreads();            // vmcnt(0) drain + publish
  cvtB();
  __syncthreads();            // Bs visible

  for (int kt = 0; kt < NT; kt++){
    int p = kt & 1;
    if (kt + 1 < NT){ issueA(kt + 1, p ^ 1); issueB(kt + 1); }  // in flight under compute
    compute(p);
    __syncthreads();          // compute reads done; gloads drained + published
    if (kt + 1 < NT) cvtB();  // Bs <- Bf (tile kt+1)
    __syncthreads();          // Bs writes visible
  }

  #pragma unroll
  for (int m = 0; m < 4; m++){
    int rloc = wr * 64 + m * 16 + (lane >> 4) * 4;
    #pragma unroll
    for (int j = 0; j < 4; j++){
      int rr = rloc + j;
      if (rr < nrows){
        size_t rowg = (size_t)(row0 + rr);
        #pragma unroll
        for (int n = 0; n < 4; n++){
          int cc = col0 + wc * 64 + n * 16 + (lane & 15);
          float v = acc[m][n][j];
          if (GELU_EP){
            float g = v * 0.5f * (1.f + erff(v * 0.70710678118f));
            outFz[rowg * N + cc] = g;
            outB[rowg * N + cc] = f2bf(g);
          } else {
            outFz[rowg * N + cc] = v;
          }
        }
      }
    }
  }
}

// ---------------- combine: sum KSPLIT partials, weighted ----------------
__global__ __launch_bounds__(256) void combine_kernel(const float* __restrict__ yp,
                                                      const int* __restrict__ dest,
                                                      const float* __restrict__ tok_p,
                                                      float* __restrict__ out){
  int t = blockIdx.x;
  int d0 = dest[2*t], d1 = dest[2*t+1];
  float p0 = tok_p[2*t], p1 = tok_p[2*t+1];
  float4 r; r.x = 0.f; r.y = 0.f; r.z = 0.f; r.w = 0.f;
  #pragma unroll
  for (int s = 0; s < KSPLIT; s++){
    float4 a = ((const float4*)(yp + ((size_t)s * M_SLOT + d0) * H_DIM))[threadIdx.x];
    float4 b = ((const float4*)(yp + ((size_t)s * M_SLOT + d1) * H_DIM))[threadIdx.x];
    r.x += p0*a.x + p1*b.x; r.y += p0*a.y + p1*b.y;
    r.z += p0*a.z + p1*b.z; r.w += p0*a.w + p1*b.w;
  }
  ((float4*)(out + (size_t)t * H_DIM))[threadIdx.x] = r;
}

extern "C" void kernel_launch(void* const* d_in, const int* in_sizes, int n_in,
                              void* d_out, int out_size, void* d_ws, size_t ws_size,
                              hipStream_t stream) {
  const float* x  = (const float*)d_in[0];
  const float* rw = (const float*)d_in[1];
  const float* w1 = (const float*)d_in[2];
  const float* w2 = (const float*)d_in[3];
  float* out_mlp  = (float*)d_out;
  float* out_gelu = (float*)d_out + (size_t)T_TOK * H_DIM;

  char* ws = (char*)d_ws;
  u16*   xg    = (u16*)(ws + 0);                     // [M+128][H] bf16
  u16*   gb    = (u16*)(ws + (9u << 20));            // [M+128][F] bf16
  float* ypart = (float*)(ws + (48u << 20));         // [2][M][H] f32
  char*  small = ws + (84u << 20);
  int*   tok_e = (int*)(small);
  float* tok_p = (float*)(small + 16384);
  int*   dest  = (int*)(small + 32768);
  u32*   partial = (u32*)(small + 49152);
  u32*   baseb   = (u32*)(small + 51200);
  int4*  tiles   = (int4*)(small + 53248);
  int*   ntiles  = (int*)(small + 54272);

  router_kernel<<<T_TOK/4, 256, 0, stream>>>(x, rw, tok_e, tok_p);
  hist_kernel<<<M_SLOT/64, 64, 0, stream>>>(tok_e, partial);
  scan_kernel<<<1, 64, 0, stream>>>(partial, baseb, tiles, ntiles);
  scatter_kernel<<<M_SLOT/64, 64, 0, stream>>>(tok_e, baseb, dest);
  gather_kernel<<<M_SLOT, 256, 0, stream>>>(x, dest, xg);
  // GEMM1: [M,1024] @ w1[e] ([1024][4096] f32, direct) + GELU
  gemmw<F_DIM, H_DIM, 16, true><<<dim3(F_DIM/128, MAXTILES, 1), 256, 0, stream>>>(
      xg, w1, tiles, ntiles, out_gelu, gb, 0);
  // GEMM2: [M,4096] @ w2[e] ([4096][1024] f32, direct), split-K=2
  gemmw<H_DIM, F_DIM, 32, false><<<dim3(H_DIM/128, MAXTILES, KSPLIT), 256, 0, stream>>>(
      gb, w2, tiles, ntiles, ypart, nullptr, (size_t)M_SLOT * H_DIM);
  combine_kernel<<<T_TOK, 256, 0, stream>>>(ypart, dest, tok_p, out_mlp);
}

// Round 8
// 253.653 us; speedup vs baseline: 1.2149x; 1.1237x over previous
//
#include <hip/hip_runtime.h>
#include <hip/hip_bf16.h>
#include <stdint.h>

typedef unsigned short u16;
typedef unsigned int u32;
typedef __attribute__((ext_vector_type(8))) short short8;
typedef __attribute__((ext_vector_type(4))) float f32x4;

#define T_TOK 2048
#define H_DIM 1024
#define F_DIM 4096
#define E_NUM 8
#define M_SLOT 4096
#define MAXTILES 24
#define KSPLIT 2

__device__ __forceinline__ u16 f2bf(float f){
  union { float f; u32 u; } v; v.f = f;
  return (u16)((v.u + 0x7FFFu + ((v.u >> 16) & 1u)) >> 16);
}

__device__ __forceinline__ void gload_lds16(const void* g, void* l){
  __builtin_amdgcn_global_load_lds(
      (const __attribute__((address_space(1))) u32*)g,
      (__attribute__((address_space(3))) u32*)l, 16, 0, 0);
}

#define SCHED0() __builtin_amdgcn_sched_barrier(0)
#define BARRIER() do { SCHED0(); __builtin_amdgcn_s_barrier(); SCHED0(); } while(0)
#define VMC6() asm volatile("s_waitcnt vmcnt(6)" ::: "memory")
#define VMC0() asm volatile("s_waitcnt vmcnt(0)" ::: "memory")

// ---------------- router ----------------
__global__ __launch_bounds__(256) void router_kernel(
    const float* __restrict__ x, const float* __restrict__ rw,
    int* __restrict__ tok_e, float* __restrict__ tok_p){
  __shared__ float wlds[E_NUM * H_DIM];
  int tid = threadIdx.x;
  for (int i = tid; i < H_DIM * E_NUM; i += 256){
    int h = i >> 3, e = i & 7;
    wlds[e * H_DIM + h] = rw[i];
  }
  __syncthreads();
  int wave = tid >> 6, lane = tid & 63;
  int t = blockIdx.x * 4 + wave;
  const float* xr = x + (size_t)t * H_DIM;
  float acc[E_NUM];
  #pragma unroll
  for (int e = 0; e < E_NUM; e++) acc[e] = 0.f;
  for (int i = 0; i < H_DIM / 64; i++){
    float xv = xr[lane + 64 * i];
    #pragma unroll
    for (int e = 0; e < E_NUM; e++) acc[e] += xv * wlds[e * H_DIM + lane + 64 * i];
  }
  #pragma unroll
  for (int e = 0; e < E_NUM; e++){
    float r = acc[e];
    #pragma unroll
    for (int off = 32; off; off >>= 1) r += __shfl_xor(r, off, 64);
    acc[e] = r;
  }
  if (lane == 0){
    float l0 = acc[0]; int e0 = 0;
    #pragma unroll
    for (int e = 1; e < E_NUM; e++) if (acc[e] > l0){ l0 = acc[e]; e0 = e; }
    float l1 = -INFINITY; int e1 = 0;
    #pragma unroll
    for (int e = 0; e < E_NUM; e++) if (e != e0 && acc[e] > l1){ l1 = acc[e]; e1 = e; }
    float ex = expf(l1 - l0);
    float inv = 1.f / (1.f + ex);
    tok_e[2*t] = e0; tok_e[2*t+1] = e1;
    tok_p[2*t] = inv; tok_p[2*t+1] = ex * inv;
  }
}

// ---------------- histogram ----------------
__global__ void hist_kernel(const int* __restrict__ tok_e, u32* __restrict__ partial){
  int lane = threadIdx.x & 63;
  int m = blockIdx.x * 64 + lane;
  int e = tok_e[m];
  #pragma unroll
  for (int ee = 0; ee < E_NUM; ee++){
    unsigned long long mk = __ballot(e == ee);
    if (lane == ee) partial[blockIdx.x * E_NUM + ee] = (u32)__popcll(mk);
  }
}

// ---------------- scan + tile table (256-row tiles) ----------------
__global__ void scan_kernel(const u32* __restrict__ partial, u32* __restrict__ baseb,
                            int4* __restrict__ tiles, int* __restrict__ ntiles){
  int lane = threadIdx.x;  // 64 threads
  u32 exc[E_NUM], tot[E_NUM];
  #pragma unroll
  for (int e = 0; e < E_NUM; e++){
    u32 v = partial[lane * E_NUM + e];
    u32 own = v;
    #pragma unroll
    for (int off = 1; off < 64; off <<= 1){
      u32 tu = __shfl_up(v, off, 64);
      if (lane >= off) v += tu;
    }
    exc[e] = v - own;
    tot[e] = __shfl(v, 63, 64);
  }
  u32 offs[E_NUM + 1]; offs[0] = 0;
  #pragma unroll
  for (int e = 0; e < E_NUM; e++) offs[e+1] = offs[e] + tot[e];
  #pragma unroll
  for (int e = 0; e < E_NUM; e++) baseb[lane * E_NUM + e] = offs[e] + exc[e];
  if (lane == 0){
    int nt = 0;
    for (int e = 0; e < E_NUM; e++){
      int cnt = (int)tot[e];
      for (int r0 = 0; r0 < cnt; r0 += 256){
        tiles[nt] = make_int4((int)offs[e] + r0, min(256, cnt - r0), e, 0);
        nt++;
      }
    }
    *ntiles = nt;
  }
}

// ---------------- scatter ----------------
__global__ void scatter_kernel(const int* __restrict__ tok_e, const u32* __restrict__ baseb,
                               int* __restrict__ dest){
  int lane = threadIdx.x & 63;
  int m = blockIdx.x * 64 + lane;
  int e = tok_e[m];
  unsigned long long eq = 0;
  #pragma unroll
  for (int ee = 0; ee < E_NUM; ee++){
    unsigned long long mk = __ballot(e == ee);
    if (e == ee) eq = mk;
  }
  u32 rank = (u32)__popcll(eq & ((1ull << lane) - 1ull));
  dest[m] = (int)(baseb[blockIdx.x * E_NUM + e] + rank);
}

// ---------------- gather ----------------
__global__ __launch_bounds__(256) void gather_kernel(const float* __restrict__ x,
                                                     const int* __restrict__ dest,
                                                     u16* __restrict__ xg){
  int m = blockIdx.x;
  int d = dest[m];
  const float4* xr = (const float4*)(x + (size_t)(m >> 1) * H_DIM);
  float4 v = xr[threadIdx.x];
  ushort4 o;
  o.x = f2bf(v.x); o.y = f2bf(v.y); o.z = f2bf(v.z); o.w = f2bf(v.w);
  ((ushort4*)(xg + (size_t)d * H_DIM))[threadIdx.x] = o;
}

// ---------------- transpose + fp32->bf16: [E][R][C] -> [E][C][R] ----------------
template<int R, int C>
__global__ __launch_bounds__(256) void transpose_cvt(const float* __restrict__ in,
                                                     u16* __restrict__ out){
  int e = blockIdx.z;
  const float* ip = in + (size_t)e * R * C;
  u16* op = out + (size_t)e * R * C;
  __shared__ u16 tile[64][66];
  int c0 = blockIdx.x * 64, r0 = blockIdx.y * 64;
  int tr = threadIdx.x >> 4, tc = threadIdx.x & 15;
  #pragma unroll
  for (int i = 0; i < 4; i++){
    int r = tr + i * 16;
    float4 v = *(const float4*)(ip + (size_t)(r0 + r) * C + c0 + tc * 4);
    tile[r][tc*4+0] = f2bf(v.x); tile[r][tc*4+1] = f2bf(v.y);
    tile[r][tc*4+2] = f2bf(v.z); tile[r][tc*4+3] = f2bf(v.w);
  }
  __syncthreads();
  #pragma unroll
  for (int i = 0; i < 4; i++){
    int c = tr + i * 16;
    ushort4 o;
    o.x = tile[tc*4+0][c]; o.y = tile[tc*4+1][c];
    o.z = tile[tc*4+2][c]; o.w = tile[tc*4+3][c];
    *(ushort4*)(op + (size_t)(c0 + c) * R + r0 + tc * 4) = o;
  }
}

// ---------------- grouped GEMM, 256x256, 8-phase, lag-3 staging ----------
// A [*][KSTRIDE] bf16; Bt [E][N][KSTRIDE] bf16. 8 waves (2 wrow x 4 wcol).
// LDS halves: 0=A rows0-127, 1=A rows128-255, 2=B cols0-127, 3=B cols128-255;
// each [128 rows][64 u16] XOR-swizzled (row&7)<<4; dbuf by tile parity.
// Frags interleave halves: A row = (m<4?0:128)+wrow*16+(m&3)*32 so phase p
// touches exactly one new half. Reads per phase: ph1 A0,B0; ph2 B1; ph3 A1;
// ph4 B0(re); ph5-8 same on odd tile.
// Staging (iter i, te=2i, to=2i+1): ph1->B0(to); ph2-5->A0,B1,A1,B0(te+2);
// ph6-8->A0,B1,A1(to+2). Every half staged >=4 phases before first read.
// vmcnt(6) only at ph4/ph8 (last iter: vmcnt(0) at ph4). Verified:
//  - prologue [A0,B1,A1,B0](t0)+[A0,B1,A1](t1), vmcnt(6) -> t0 landed.
//  - iter ph4 vmcnt(6): outstanding = ph2,3,4 stages -> all of tile(to) landed.
//  - iter ph8 vmcnt(6): outstanding = ph6,7,8 stages -> tile(te+2) A0..B0 landed.
//  - tenancy: each stage targets a half whose last LDS read was the previous
//    phase (barrier-separated); reads drain at each phase's pre-MFMA lgkmcnt.
template<int N, int KSTRIDE, int NT, bool GELU_EP>
__global__ __launch_bounds__(512, 2) void gemm8(
    const u16* __restrict__ A, const u16* __restrict__ Bt,
    const int4* __restrict__ tiles, const int* __restrict__ ntiles_p,
    float* __restrict__ outF, u16* __restrict__ outB, size_t zstride){
  if ((int)blockIdx.y >= *ntiles_p) return;
  int4 ti = tiles[blockIdx.y];
  int row0 = ti.x, nrows = ti.y, e = ti.z;
  int col0 = blockIdx.x * 256;
  size_t kofs = (size_t)blockIdx.z * ((size_t)NT * 64);
  const u16* Be = Bt + (size_t)e * N * KSTRIDE;
  float* outFz = outF + (size_t)blockIdx.z * zstride;

  __shared__ __align__(16) u16 lds[2][4][128 * 64];

  int tid = threadIdx.x, lane = tid & 63, wid = tid >> 6;
  int wrow = wid >> 2, wcol = wid & 3;

  auto stg = [&](int p, int half, int kt){
    const u16* gb_; int rb;
    if (half < 2){ gb_ = A;  rb = row0 + half * 128; }
    else         { gb_ = Be; rb = col0 + (half - 2) * 128; }
    #pragma unroll
    for (int j = 0; j < 2; j++){
      int crow = j * 64 + wid * 8 + (lane >> 3);
      int cb = ((lane & 7) * 16) ^ ((lane >> 3) << 4);
      const char* g = (const char*)(gb_ + (size_t)(rb + crow) * KSTRIDE + kofs + (size_t)kt * 64) + cb;
      u16* l = (u16*)&lds[p][half][0] + (size_t)(j * 512 + wid * 64) * 8;
      gload_lds16(g, l);
    }
  };

  auto frd = [&](int p, int half, int rb16, int kk)->short8{
    int row = rb16 + (lane & 15);
    int byte_ = row * 128 + ((kk * 64 + (lane >> 4) * 16) ^ ((lane & 7) << 4));
    return *(const short8*)((const char*)&lds[p][half][0] + byte_);
  };

  f32x4 acc[8][4];
  #pragma unroll
  for (int m = 0; m < 8; m++)
    #pragma unroll
    for (int n = 0; n < 4; n++) acc[m][n] = (f32x4)0.f;

  short8 a[4][2], b[4][2];

  // prologue: steady-state issue-order roles [prev ph2..ph8]
  stg(0, 0, 0); stg(0, 3, 0); stg(0, 1, 0); stg(0, 2, 0);   // A0,B1,A1,B0 of t0
  stg(1, 0, 1); stg(1, 3, 1); stg(1, 1, 1);                 // A0,B1,A1 of t1
  VMC6();            // oldest 8 loads landed = all of tile 0
  BARRIER();

  constexpr int NI = NT / 2;
  for (int i = 0; i < NI; i++){
    int te = 2 * i, to = 2 * i + 1;
    bool pre = (i + 1 < NI);
    // ---------- ph1: Q00 even (reads A0,B0 of buf0)
    #pragma unroll
    for (int m = 0; m < 4; m++)
      #pragma unroll
      for (int kk = 0; kk < 2; kk++) a[m][kk] = frd(0, 0, wrow * 16 + m * 32, kk);
    #pragma unroll
    for (int n = 0; n < 2; n++)
      #pragma unroll
      for (int kk = 0; kk < 2; kk++) b[n][kk] = frd(0, 2, wcol * 16 + n * 64, kk);
    stg(1, 2, to);                               // B0 of odd tile (read ph5)
    BARRIER();
    __builtin_amdgcn_s_setprio(1);
    #pragma unroll
    for (int m = 0; m < 4; m++)
      #pragma unroll
      for (int n = 0; n < 2; n++)
        #pragma unroll
        for (int kk = 0; kk < 2; kk++)
          acc[m][n] = __builtin_amdgcn_mfma_f32_16x16x32_bf16(a[m][kk], b[n][kk], acc[m][n], 0, 0, 0);
    __builtin_amdgcn_s_setprio(0);
    BARRIER();
    // ---------- ph2: Q01 even (reads B1)
    #pragma unroll
    for (int n = 2; n < 4; n++)
      #pragma unroll
      for (int kk = 0; kk < 2; kk++) b[n][kk] = frd(0, 3, wcol * 16 + (n - 2) * 64, kk);
    if (pre) stg(0, 0, te + 2);
    BARRIER();
    __builtin_amdgcn_s_setprio(1);
    #pragma unroll
    for (int m = 0; m < 4; m++)
      #pragma unroll
      for (int n = 2; n < 4; n++)
        #pragma unroll
        for (int kk = 0; kk < 2; kk++)
          acc[m][n] = __builtin_amdgcn_mfma_f32_16x16x32_bf16(a[m][kk], b[n][kk], acc[m][n], 0, 0, 0);
    __builtin_amdgcn_s_setprio(0);
    BARRIER();
    // ---------- ph3: Q11 even (reads A1)
    #pragma unroll
    for (int m = 0; m < 4; m++)
      #pragma unroll
      for (int kk = 0; kk < 2; kk++) a[m][kk] = frd(0, 1, wrow * 16 + m * 32, kk);
    if (pre) stg(0, 3, te + 2);
    BARRIER();
    __builtin_amdgcn_s_setprio(1);
    #pragma unroll
    for (int m = 0; m < 4; m++)
      #pragma unroll
      for (int n = 2; n < 4; n++)
        #pragma unroll
        for (int kk = 0; kk < 2; kk++)
          acc[m + 4][n] = __builtin_amdgcn_mfma_f32_16x16x32_bf16(a[m][kk], b[n][kk], acc[m + 4][n], 0, 0, 0);
    __builtin_amdgcn_s_setprio(0);
    BARRIER();
    // ---------- ph4: Q10 even (re-reads B0)
    #pragma unroll
    for (int n = 0; n < 2; n++)
      #pragma unroll
      for (int kk = 0; kk < 2; kk++) b[n][kk] = frd(0, 2, wcol * 16 + n * 64, kk);
    if (pre) stg(0, 1, te + 2);
    BARRIER();
    __builtin_amdgcn_s_setprio(1);
    #pragma unroll
    for (int m = 0; m < 4; m++)
      #pragma unroll
      for (int n = 0; n < 2; n++)
        #pragma unroll
        for (int kk = 0; kk < 2; kk++)
          acc[m + 4][n] = __builtin_amdgcn_mfma_f32_16x16x32_bf16(a[m][kk], b[n][kk], acc[m + 4][n], 0, 0, 0);
    __builtin_amdgcn_s_setprio(0);
    if (pre) { VMC6(); } else { VMC0(); }        // tile(to) halves landed
    BARRIER();
    // ---------- ph5: Q00 odd
    #pragma unroll
    for (int m = 0; m < 4; m++)
      #pragma unroll
      for (int kk = 0; kk < 2; kk++) a[m][kk] = frd(1, 0, wrow * 16 + m * 32, kk);
    #pragma unroll
    for (int n = 0; n < 2; n++)
      #pragma unroll
      for (int kk = 0; kk < 2; kk++) b[n][kk] = frd(1, 2, wcol * 16 + n * 64, kk);
    if (pre) stg(0, 2, te + 2);
    BARRIER();
    __builtin_amdgcn_s_setprio(1);
    #pragma unroll
    for (int m = 0; m < 4; m++)
      #pragma unroll
      for (int n = 0; n < 2; n++)
        #pragma unroll
        for (int kk = 0; kk < 2; kk++)
          acc[m][n] = __builtin_amdgcn_mfma_f32_16x16x32_bf16(a[m][kk], b[n][kk], acc[m][n], 0, 0, 0);
    __builtin_amdgcn_s_setprio(0);
    BARRIER();
    // ---------- ph6: Q01 odd
    #pragma unroll
    for (int n = 2; n < 4; n++)
      #pragma unroll
      for (int kk = 0; kk < 2; kk++) b[n][kk] = frd(1, 3, wcol * 16 + (n - 2) * 64, kk);
    if (pre) stg(1, 0, to + 2);
    BARRIER();
    __builtin_amdgcn_s_setprio(1);
    #pragma unroll
    for (int m = 0; m < 4; m++)
      #pragma unroll
      for (int n = 2; n < 4; n++)
        #pragma unroll
        for (int kk = 0; kk < 2; kk++)
          acc[m][n] = __builtin_amdgcn_mfma_f32_16x16x32_bf16(a[m][kk], b[n][kk], acc[m][n], 0, 0, 0);
    __builtin_amdgcn_s_setprio(0);
    BARRIER();
    // ---------- ph7: Q11 odd
    #pragma unroll
    for (int m = 0; m < 4; m++)
      #pragma unroll
      for (int kk = 0; kk < 2; kk++) a[m][kk] = frd(1, 1, wrow * 16 + m * 32, kk);
    if (pre) stg(1, 3, to + 2);
    BARRIER();
    __builtin_amdgcn_s_setprio(1);
    #pragma unroll
    for (int m = 0; m < 4; m++)
      #pragma unroll
      for (int n = 2; n < 4; n++)
        #pragma unroll
        for (int kk = 0; kk < 2; kk++)
          acc[m + 4][n] = __builtin_amdgcn_mfma_f32_16x16x32_bf16(a[m][kk], b[n][kk], acc[m + 4][n], 0, 0, 0);
    __builtin_amdgcn_s_setprio(0);
    BARRIER();
    // ---------- ph8: Q10 odd
    #pragma unroll
    for (int n = 0; n < 2; n++)
      #pragma unroll
      for (int kk = 0; kk < 2; kk++) b[n][kk] = frd(1, 2, wcol * 16 + n * 64, kk);
    if (pre) stg(1, 1, to + 2);
    BARRIER();
    __builtin_amdgcn_s_setprio(1);
    #pragma unroll
    for (int m = 0; m < 4; m++)
      #pragma unroll
      for (int n = 0; n < 2; n++)
        #pragma unroll
        for (int kk = 0; kk < 2; kk++)
          acc[m + 4][n] = __builtin_amdgcn_mfma_f32_16x16x32_bf16(a[m][kk], b[n][kk], acc[m + 4][n], 0, 0, 0);
    __builtin_amdgcn_s_setprio(0);
    if (pre) { VMC6(); }                         // tile(te+2) halves landed
    BARRIER();
  }

  // epilogue
  #pragma unroll
  for (int m = 0; m < 8; m++){
    int rloc = ((m < 4) ? 0 : 128) + wrow * 16 + (m & 3) * 32 + (lane >> 4) * 4;
    #pragma unroll
    for (int j = 0; j < 4; j++){
      int rr = rloc + j;
      if (rr < nrows){
        size_t rowg = (size_t)(row0 + rr);
        #pragma unroll
        for (int n = 0; n < 4; n++){
          int cc = col0 + ((n < 2) ? 0 : 128) + wcol * 16 + (n & 1) * 64 + (lane & 15);
          float v = acc[m][n][j];
          if (GELU_EP){
            float g = v * 0.5f * (1.f + erff(v * 0.70710678118f));
            outFz[rowg * N + cc] = g;
            outB[rowg * N + cc] = f2bf(g);
          } else {
            outFz[rowg * N + cc] = v;
          }
        }
      }
    }
  }
}

// ---------------- combine: sum KSPLIT partials, weighted ----------------
__global__ __launch_bounds__(256) void combine_kernel(const float* __restrict__ yp,
                                                      const int* __restrict__ dest,
                                                      const float* __restrict__ tok_p,
                                                      float* __restrict__ out){
  int t = blockIdx.x;
  int d0 = dest[2*t], d1 = dest[2*t+1];
  float p0 = tok_p[2*t], p1 = tok_p[2*t+1];
  float4 r; r.x = 0.f; r.y = 0.f; r.z = 0.f; r.w = 0.f;
  #pragma unroll
  for (int s = 0; s < KSPLIT; s++){
    float4 a = ((const float4*)(yp + ((size_t)s * M_SLOT + d0) * H_DIM))[threadIdx.x];
    float4 b = ((const float4*)(yp + ((size_t)s * M_SLOT + d1) * H_DIM))[threadIdx.x];
    r.x += p0*a.x + p1*b.x; r.y += p0*a.y + p1*b.y;
    r.z += p0*a.z + p1*b.z; r.w += p0*a.w + p1*b.w;
  }
  ((float4*)(out + (size_t)t * H_DIM))[threadIdx.x] = r;
}

extern "C" void kernel_launch(void* const* d_in, const int* in_sizes, int n_in,
                              void* d_out, int out_size, void* d_ws, size_t ws_size,
                              hipStream_t stream) {
  const float* x  = (const float*)d_in[0];
  const float* rw = (const float*)d_in[1];
  const float* w1 = (const float*)d_in[2];
  const float* w2 = (const float*)d_in[3];
  float* out_mlp  = (float*)d_out;
  float* out_gelu = (float*)d_out + (size_t)T_TOK * H_DIM;

  char* ws = (char*)d_ws;
  // ypart aliases w1t (w1t dead after GEMM1; ypart written by GEMM2)
  u16*   w1t   = (u16*)(ws + 0);                 // [E][F][H] bf16, 64 MB
  float* ypart = (float*)(ws + 0);               // [2][M][H] f32,  32 MB (alias)
  u16*   w2t   = (u16*)(ws + 67108864);          // [E][H][F] bf16, 64 MB
  u16*   xg    = (u16*)(ws + 134217728);         // [M+256][H] bf16
  u16*   gb    = (u16*)(ws + 143130624);         // [M+256][F] bf16
  char*  small = ws + 178782208;
  int*   tok_e = (int*)(small);
  float* tok_p = (float*)(small + 16384);
  int*   dest  = (int*)(small + 32768);
  u32*   partial = (u32*)(small + 49152);
  u32*   baseb   = (u32*)(small + 51200);
  int4*  tiles   = (int4*)(small + 53248);
  int*   ntiles  = (int*)(small + 54272);

  router_kernel<<<T_TOK/4, 256, 0, stream>>>(x, rw, tok_e, tok_p);
  hist_kernel<<<M_SLOT/64, 64, 0, stream>>>(tok_e, partial);
  scan_kernel<<<1, 64, 0, stream>>>(partial, baseb, tiles, ntiles);
  scatter_kernel<<<M_SLOT/64, 64, 0, stream>>>(tok_e, baseb, dest);
  gather_kernel<<<M_SLOT, 256, 0, stream>>>(x, dest, xg);
  // transpose w1 immediately before GEMM1 (w1t L3-warm)
  transpose_cvt<H_DIM, F_DIM><<<dim3(F_DIM/64, H_DIM/64, E_NUM), 256, 0, stream>>>(w1, w1t);
  gemm8<F_DIM, H_DIM, 16, true><<<dim3(F_DIM/256, MAXTILES, 1), 512, 0, stream>>>(
      xg, w1t, tiles, ntiles, out_gelu, gb, 0);
  // transpose w2 immediately before GEMM2 (w2t L3-warm)
  transpose_cvt<F_DIM, H_DIM><<<dim3(H_DIM/64, F_DIM/64, E_NUM), 256, 0, stream>>>(w2, w2t);
  gemm8<H_DIM, F_DIM, 32, false><<<dim3(H_DIM/256, MAXTILES, KSPLIT), 512, 0, stream>>>(
      gb, w2t, tiles, ntiles, ypart, nullptr, (size_t)M_SLOT * H_DIM);
  combine_kernel<<<T_TOK, 256, 0, stream>>>(ypart, dest, tok_p, out_mlp);
}